// Round 1
// baseline (356.123 us; speedup 1.0000x reference)
//
#include <hip/hip_runtime.h>
#include <math.h>

#define BB 1024
#define TT 512
#define CC 53
#define BOS 1
#define EOS 2

__global__ __launch_bounds__(64) void crf_batch_kernel(
    const float* __restrict__ em,     // B,T,C
    const int*   __restrict__ tags,   // B,T
    const float* __restrict__ mask,   // B,T
    const float* __restrict__ trans,  // C,C
    float*       __restrict__ partial) // B  (partition - score)
{
    const int b = blockIdx.x;
    const int lane = threadIdx.x;           // 0..63
    const int cc = lane < CC ? lane : CC - 1; // lanes >= C mirror lane 52

    __shared__ float p_sh[64];

    // ---- length = sum(mask[b,:]) (exact: entries are 0.0/1.0) ----
    const float* mrow = mask + (size_t)b * TT;
    float msum = 0.f;
    #pragma unroll
    for (int i = 0; i < TT / 64; ++i) msum += mrow[lane + 64 * i];
    #pragma unroll
    for (int o = 32; o > 0; o >>= 1) msum += __shfl_xor(msum, o);
    const int len = (int)(msum + 0.5f);     // in [256, 511]

    // ---- score (gather part), lane-parallel over t ----
    const int* trow = tags + (size_t)b * TT;
    const float* ep = em + (size_t)b * TT * CC;
    float sc = 0.f;
    for (int t = 2 + lane; t < len; t += 64) {
        int tg = trow[t];
        int tp = trow[t - 1];
        sc += ep[(size_t)t * CC + tg] + trans[tp * CC + tg];
    }
    #pragma unroll
    for (int o = 32; o > 0; o >>= 1) sc += __shfl_xor(sc, o);
    if (lane == 0) {
        int t1 = trow[1];
        sc += trans[BOS * CC + t1] + ep[1 * CC + t1];   // "first"
        int tl = trow[len];
        sc += trans[tl * CC + EOS];                      // "last"
    }

    // ---- W[c'][lane] = exp(trans[c', lane]) in registers ----
    float w[CC];
    #pragma unroll
    for (int i = 0; i < CC; ++i) w[i] = __expf(trans[i * CC + cc]);

    // ---- alpha init (t = 1 row) ----
    float alpha = trans[BOS * CC + cc] + ep[1 * CC + cc];

    // ---- forward scan t = 2 .. len-1 ----
    float e_cur = ep[2 * CC + cc];
    for (int t = 2; t < len; ++t) {
        // prefetch next emission row (t+1 <= len <= 511, always in-bounds)
        float e_next = ep[(size_t)(t + 1) * CC + cc];

        float M = __uint_as_float(__builtin_amdgcn_readfirstlane(__float_as_uint(alpha)));
        float p = __expf(alpha - M);        // |alpha - M| bounded (~16), safe
        p_sh[lane] = p;
        __syncthreads();

        float a0 = 0.f, a1 = 0.f, a2 = 0.f, a3 = 0.f;
        const float4* p4 = (const float4*)p_sh;
        #pragma unroll
        for (int i = 0; i < 13; ++i) {
            float4 q = p4[i];                // broadcast reads, conflict-free
            a0 = fmaf(q.x, w[4 * i + 0], a0);
            a1 = fmaf(q.y, w[4 * i + 1], a1);
            a2 = fmaf(q.z, w[4 * i + 2], a2);
            a3 = fmaf(q.w, w[4 * i + 3], a3);
        }
        a0 = fmaf(p_sh[52], w[52], a0);
        float acc = (a0 + a1) + (a2 + a3);   // > 0 always (lane-0 term ~ 1)

        alpha = M + __logf(acc) + e_cur;
        e_cur = e_next;
        __syncthreads();                     // protect p_sh overwrite (WAR)
    }

    // ---- partition = logsumexp_c(alpha[c] + trans[c, EOS]) ----
    float v = (lane < CC) ? alpha + trans[cc * CC + EOS] : -INFINITY;
    float mv = v;
    #pragma unroll
    for (int o = 32; o > 0; o >>= 1) mv = fmaxf(mv, __shfl_xor(mv, o));
    float s = __expf(v - mv);                // idle lanes: exp(-inf)=0
    #pragma unroll
    for (int o = 32; o > 0; o >>= 1) s += __shfl_xor(s, o);
    float logZ = mv + __logf(s);

    if (lane == 0) partial[b] = logZ - sc;
}

__global__ __launch_bounds__(256) void crf_reduce_kernel(
    const float* __restrict__ partial, float* __restrict__ out)
{
    float s = 0.f;
    #pragma unroll
    for (int k = 0; k < BB / 256; ++k) s += partial[threadIdx.x + 256 * k];
    #pragma unroll
    for (int o = 32; o > 0; o >>= 1) s += __shfl_xor(s, o);
    __shared__ float wsum[4];
    if ((threadIdx.x & 63) == 0) wsum[threadIdx.x >> 6] = s;
    __syncthreads();
    if (threadIdx.x == 0) out[0] = (wsum[0] + wsum[1]) + (wsum[2] + wsum[3]);
}

extern "C" void kernel_launch(void* const* d_in, const int* in_sizes, int n_in,
                              void* d_out, int out_size, void* d_ws, size_t ws_size,
                              hipStream_t stream) {
    const float* em    = (const float*)d_in[0];
    const int*   tags  = (const int*)d_in[1];
    const float* mask  = (const float*)d_in[2];
    const float* trans = (const float*)d_in[3];
    float* out = (float*)d_out;
    float* partial = (float*)d_ws;   // B floats of scratch

    crf_batch_kernel<<<BB, 64, 0, stream>>>(em, tags, mask, trans, partial);
    crf_reduce_kernel<<<1, 256, 0, stream>>>(partial, out);
}